// Round 2
// baseline (615.382 us; speedup 1.0000x reference)
//
#include <hip/hip_runtime.h>

// Node2Edge2Node GNN block, MI355X (gfx950).
// Pipeline: prep (bf16 casts + MFMA-layout weight packing) -> CSR build by dst
// (hist/scan/fill) -> per-node edge GEMM with MFMA accumulation (no scatter
// atomics) -> self-term GEMM (x@W1b folded out of edge GEMM) -> node GEMM.
//
// R1 fix: b1 was double-counted (k_edge adds cnt*b1 AND k_selfterm added
// cnt*(...+b1)). k_selfterm now adds only cnt * (x[v] @ W1b).

#define NN 10000
#define ED 640000
#define D  128

typedef __bf16 bf16;
typedef bf16  bf16x8 __attribute__((ext_vector_type(8)));
typedef float f32x4  __attribute__((ext_vector_type(4)));

__device__ __forceinline__ bf16 f2b(float f) {
  unsigned u = __builtin_bit_cast(unsigned, f);
  u += 0x7fffu + ((u >> 16) & 1u);               // RTNE
  unsigned short h = (unsigned short)(u >> 16);
  return __builtin_bit_cast(bf16, h);
}

__device__ __forceinline__ bf16x8 bzero8() {
  bf16 z = __builtin_bit_cast(bf16, (unsigned short)0);
  bf16x8 v = {z, z, z, z, z, z, z, z};
  return v;
}

// ---------------------------------------------------------------------------
// K1: convert x -> bf16; zero counts; pack W1 (k-rows 0..127 & 256..383),
// W1b (rows 128..255), W2 into MFMA B-frag layout:
//   Bp[((kb*8 + t)*64 + L)*8 + j] = W[k = kb*32 + (L>>4)*8 + j][n = t*16 + (L&15)]
// ---------------------------------------------------------------------------
__global__ __launch_bounds__(256) void k_prep(const float* __restrict__ x,
                                              const float* __restrict__ W1,
                                              const float* __restrict__ W2,
                                              bf16* __restrict__ xb,
                                              bf16* __restrict__ W1p,
                                              bf16* __restrict__ W1bp,
                                              bf16* __restrict__ W2p,
                                              int* __restrict__ counts) {
  int id = blockIdx.x * 256 + threadIdx.x;
  if (id < 160000) {                    // xb: 10000*128/8 chunks
    int i = id * 8;
    f32x4 a = *(const f32x4*)(x + i);
    f32x4 b = *(const f32x4*)(x + i + 4);
    bf16x8 h;
    h[0]=f2b(a[0]); h[1]=f2b(a[1]); h[2]=f2b(a[2]); h[3]=f2b(a[3]);
    h[4]=f2b(b[0]); h[5]=f2b(b[1]); h[6]=f2b(b[2]); h[7]=f2b(b[3]);
    *(bf16x8*)(xb + i) = h;
  } else if (id < 170000) {             // zero counts
    counts[id - 160000] = 0;
  } else if (id < 174096) {             // W1p: kb 0..7 -> W1 rows 0..127,256..383
    int o8 = id - 170000;
    int kb = o8 >> 9, rem = o8 & 511, t = rem >> 6, L = rem & 63;
    int col = t * 16 + (L & 15);
    int k0  = kb * 32 + (L >> 4) * 8;
    int row0 = (kb < 4) ? k0 : (k0 + 128);
    bf16x8 h;
    #pragma unroll
    for (int j = 0; j < 8; j++) h[j] = f2b(W1[(row0 + j) * D + col]);
    *(bf16x8*)(W1p + o8 * 8) = h;
  } else if (id < 176144) {             // W1bp: W1 rows 128..255
    int o8 = id - 174096;
    int kb = o8 >> 9, rem = o8 & 511, t = rem >> 6, L = rem & 63;
    int col = t * 16 + (L & 15);
    int row0 = 128 + kb * 32 + (L >> 4) * 8;
    bf16x8 h;
    #pragma unroll
    for (int j = 0; j < 8; j++) h[j] = f2b(W1[(row0 + j) * D + col]);
    *(bf16x8*)(W1bp + o8 * 8) = h;
  } else if (id < 180240) {             // W2p: rows 0..255
    int o8 = id - 176144;
    int kb = o8 >> 9, rem = o8 & 511, t = rem >> 6, L = rem & 63;
    int col = t * 16 + (L & 15);
    int row0 = kb * 32 + (L >> 4) * 8;
    bf16x8 h;
    #pragma unroll
    for (int j = 0; j < 8; j++) h[j] = f2b(W2[(row0 + j) * D + col]);
    *(bf16x8*)(W2p + o8 * 8) = h;
  }
}

// K2: histogram of dst
__global__ __launch_bounds__(256) void k_hist(const int* __restrict__ dst,
                                              int* __restrict__ counts) {
  int e = blockIdx.x * 256 + threadIdx.x;
  if (e < ED) atomicAdd(&counts[dst[e]], 1);
}

// K3: single-block exclusive scan -> row_ptr, fill_ptr
__global__ __launch_bounds__(256) void k_scan(const int* __restrict__ counts,
                                              int* __restrict__ row_ptr,
                                              int* __restrict__ fill_ptr) {
  __shared__ int part[256];
  int tid = threadIdx.x;
  const int CH = 40;                    // 256*40 = 10240 >= NN
  int base = tid * CH;
  int sum = 0;
  for (int i = 0; i < CH; i++) { int idx = base + i; if (idx < NN) sum += counts[idx]; }
  part[tid] = sum;
  __syncthreads();
  for (int off = 1; off < 256; off <<= 1) {
    int v = (tid >= off) ? part[tid - off] : 0;
    __syncthreads();
    part[tid] += v;
    __syncthreads();
  }
  int run = part[tid] - sum;            // exclusive prefix
  for (int i = 0; i < CH; i++) {
    int idx = base + i;
    if (idx < NN) { row_ptr[idx] = run; fill_ptr[idx] = run; run += counts[idx]; }
  }
  if (tid == 255) row_ptr[NN] = part[255];
}

// K4: scatter edges into CSR order (also gather src ids)
__global__ __launch_bounds__(256) void k_fill(const int* __restrict__ src,
                                              const int* __restrict__ dst,
                                              int* __restrict__ fill_ptr,
                                              int* __restrict__ csr_eid,
                                              int* __restrict__ csr_src) {
  int e = blockIdx.x * 256 + threadIdx.x;
  if (e < ED) {
    int d = dst[e];
    int pos = atomicAdd(&fill_ptr[d], 1);
    csr_eid[pos] = e;
    csr_src[pos] = src[e];
  }
}

// ---------------------------------------------------------------------------
// K5: per-node edge GEMM.  agg'[v] = sum_{e->v} [ x[src_e] | ea_e ] @ W1ac
// Block = 256 thr (4 waves). Wave w owns cols 32w..32w+31 (n-tiles 2w,2w+1).
// M-tiles of 16 edges accumulate into the SAME C-frags (rows later summed).
// B-frags (16) live in VGPRs, loaded once per block from packed W1p.
// ---------------------------------------------------------------------------
#define K5_GRID 2048
__global__ __launch_bounds__(256) void k_edge(const bf16*  __restrict__ xb,
                                              const float* __restrict__ ea,
                                              const bf16*  __restrict__ W1p,
                                              const float* __restrict__ b1,
                                              const int*   __restrict__ row_ptr,
                                              const int*   __restrict__ csr_eid,
                                              const int*   __restrict__ csr_src,
                                              float* __restrict__ agg) {
  __shared__ __align__(16) bf16 As[16][264];   // 256 + 8 pad (stride 132 dw -> 2-way, free)
  int tid  = threadIdx.x;
  int wave = tid >> 6, lane = tid & 63, quad = lane >> 4, l16 = lane & 15;
  int srow = tid >> 4, scol = tid & 15;        // staging: 16 rows x 16 chunks

  bf16x8 B[8][2];
  #pragma unroll
  for (int kb = 0; kb < 8; kb++)
    #pragma unroll
    for (int tt = 0; tt < 2; tt++)
      B[kb][tt] = *(const bf16x8*)(W1p + ((kb * 8 + (wave * 2 + tt)) * 64 + lane) * 8);

  for (int v = blockIdx.x; v < NN; v += K5_GRID) {
    int e0 = row_ptr[v], e1 = row_ptr[v + 1];
    int cnt = e1 - e0;
    f32x4 acc0 = {0.f, 0.f, 0.f, 0.f};
    f32x4 acc1 = {0.f, 0.f, 0.f, 0.f};
    int ntile = (cnt + 15) >> 4;
    for (int t = 0; t < ntile; t++) {
      int e = e0 + t * 16 + srow;
      if (e < e1) {
        int eid = csr_eid[e];
        int sid = csr_src[e];
        // seg0: gathered source-node features (bf16, L2-resident)
        *(bf16x8*)&As[srow][scol * 8] = *(const bf16x8*)(xb + sid * D + scol * 8);
        // seg1: edge features fp32 -> bf16 (the big HBM stream)
        const float* ep = ea + (size_t)eid * D + scol * 8;
        f32x4 f0 = *(const f32x4*)ep;
        f32x4 f1 = *(const f32x4*)(ep + 4);
        bf16x8 h;
        h[0]=f2b(f0[0]); h[1]=f2b(f0[1]); h[2]=f2b(f0[2]); h[3]=f2b(f0[3]);
        h[4]=f2b(f1[0]); h[5]=f2b(f1[1]); h[6]=f2b(f1[2]); h[7]=f2b(f1[3]);
        *(bf16x8*)&As[srow][128 + scol * 8] = h;
      } else {
        bf16x8 z = bzero8();
        *(bf16x8*)&As[srow][scol * 8] = z;
        *(bf16x8*)&As[srow][128 + scol * 8] = z;
      }
      __syncthreads();
      #pragma unroll
      for (int kb = 0; kb < 8; kb++) {
        bf16x8 a = *(const bf16x8*)&As[l16][kb * 32 + quad * 8];
        acc0 = __builtin_amdgcn_mfma_f32_16x16x32_bf16(a, B[kb][0], acc0, 0, 0, 0);
        acc1 = __builtin_amdgcn_mfma_f32_16x16x32_bf16(a, B[kb][1], acc1, 0, 0, 0);
      }
      __syncthreads();
    }
    // reduce the 16 rows (edges) of each C-frag: regs then lanes (quads)
    float s0 = acc0[0] + acc0[1] + acc0[2] + acc0[3];
    float s1 = acc1[0] + acc1[1] + acc1[2] + acc1[3];
    s0 += __shfl_xor(s0, 16, 64);  s0 += __shfl_xor(s0, 32, 64);
    s1 += __shfl_xor(s1, 16, 64);  s1 += __shfl_xor(s1, 32, 64);
    int cbase = wave * 32;
    if (lane < 16) {
      int c = cbase + lane;
      agg[v * D + c] = s0 + (float)cnt * b1[c];
    } else if (lane < 32) {
      int c = cbase + 16 + (lane & 15);
      agg[v * D + c] = s1 + (float)cnt * b1[c];
    }
  }
}

// ---------------------------------------------------------------------------
// K5b: agg[v] += cnt_v * (x[v] @ W1b)   (the h_j = x[dst] term, folded).
// NOTE: cnt*b1 is already added by k_edge — do NOT add it again here.
// 64 nodes per block, K=128.
// ---------------------------------------------------------------------------
__global__ __launch_bounds__(256) void k_selfterm(const bf16* __restrict__ xb,
                                                  const bf16* __restrict__ W1bp,
                                                  const int*  __restrict__ row_ptr,
                                                  float* __restrict__ agg) {
  __shared__ __align__(16) bf16 As[64][136];   // 128 + 8 pad
  int tid  = threadIdx.x;
  int wave = tid >> 6, lane = tid & 63, quad = lane >> 4, l16 = lane & 15;
  int n0 = blockIdx.x * 64;

  bf16x8 B[4][2];
  #pragma unroll
  for (int kb = 0; kb < 4; kb++)
    #pragma unroll
    for (int tt = 0; tt < 2; tt++)
      B[kb][tt] = *(const bf16x8*)(W1bp + ((kb * 8 + (wave * 2 + tt)) * 64 + lane) * 8);

  #pragma unroll
  for (int i = 0; i < 4; i++) {
    int g = tid + 256 * i;
    int row = g >> 4, c8 = g & 15;
    int v = n0 + row;
    bf16x8 h = (v < NN) ? *(const bf16x8*)(xb + v * D + c8 * 8) : bzero8();
    *(bf16x8*)&As[row][c8 * 8] = h;
  }
  __syncthreads();

  f32x4 acc[4][2];
  #pragma unroll
  for (int mt = 0; mt < 4; mt++)
    #pragma unroll
    for (int tt = 0; tt < 2; tt++) acc[mt][tt] = (f32x4){0.f, 0.f, 0.f, 0.f};

  #pragma unroll
  for (int kb = 0; kb < 4; kb++)
    #pragma unroll
    for (int mt = 0; mt < 4; mt++) {
      bf16x8 a = *(const bf16x8*)&As[mt * 16 + l16][kb * 32 + quad * 8];
      acc[mt][0] = __builtin_amdgcn_mfma_f32_16x16x32_bf16(a, B[kb][0], acc[mt][0], 0, 0, 0);
      acc[mt][1] = __builtin_amdgcn_mfma_f32_16x16x32_bf16(a, B[kb][1], acc[mt][1], 0, 0, 0);
    }

  #pragma unroll
  for (int mt = 0; mt < 4; mt++)
    #pragma unroll
    for (int tt = 0; tt < 2; tt++)
      #pragma unroll
      for (int r = 0; r < 4; r++) {
        int v = n0 + mt * 16 + quad * 4 + r;
        if (v < NN) {
          int c = wave * 32 + tt * 16 + l16;
          float cntf = (float)(row_ptr[v + 1] - row_ptr[v]);
          agg[v * D + c] += cntf * acc[mt][tt][r];   // b1 already in k_edge
        }
      }
}

// ---------------------------------------------------------------------------
// K6: out = [agg | x] @ W2 + b2.  64 nodes per block, K=256.
// ---------------------------------------------------------------------------
__global__ __launch_bounds__(256) void k_node(const float* __restrict__ agg,
                                              const bf16*  __restrict__ xb,
                                              const bf16*  __restrict__ W2p,
                                              const float* __restrict__ b2,
                                              float* __restrict__ out) {
  __shared__ __align__(16) bf16 As[64][264];
  int tid  = threadIdx.x;
  int wave = tid >> 6, lane = tid & 63, quad = lane >> 4, l16 = lane & 15;
  int n0 = blockIdx.x * 64;

  bf16x8 B[8][2];
  #pragma unroll
  for (int kb = 0; kb < 8; kb++)
    #pragma unroll
    for (int tt = 0; tt < 2; tt++)
      B[kb][tt] = *(const bf16x8*)(W2p + ((kb * 8 + (wave * 2 + tt)) * 64 + lane) * 8);

  #pragma unroll
  for (int i = 0; i < 8; i++) {
    int g = tid + 256 * i;
    int row = g >> 5, c8 = g & 31;
    int v = n0 + row;
    if (c8 < 16) {                       // seg0: agg (f32 -> bf16)
      bf16x8 h;
      if (v < NN) {
        const float* ap = agg + v * D + c8 * 8;
        f32x4 f0 = *(const f32x4*)ap;
        f32x4 f1 = *(const f32x4*)(ap + 4);
        h[0]=f2b(f0[0]); h[1]=f2b(f0[1]); h[2]=f2b(f0[2]); h[3]=f2b(f0[3]);
        h[4]=f2b(f1[0]); h[5]=f2b(f1[1]); h[6]=f2b(f1[2]); h[7]=f2b(f1[3]);
      } else h = bzero8();
      *(bf16x8*)&As[row][c8 * 8] = h;
    } else {                             // seg1: x (bf16)
      int c8b = c8 - 16;
      bf16x8 h = (v < NN) ? *(const bf16x8*)(xb + v * D + c8b * 8) : bzero8();
      *(bf16x8*)&As[row][128 + c8b * 8] = h;
    }
  }
  __syncthreads();

  f32x4 acc[4][2];
  #pragma unroll
  for (int mt = 0; mt < 4; mt++)
    #pragma unroll
    for (int tt = 0; tt < 2; tt++) acc[mt][tt] = (f32x4){0.f, 0.f, 0.f, 0.f};

  #pragma unroll
  for (int kb = 0; kb < 8; kb++)
    #pragma unroll
    for (int mt = 0; mt < 4; mt++) {
      bf16x8 a = *(const bf16x8*)&As[mt * 16 + l16][kb * 32 + quad * 8];
      acc[mt][0] = __builtin_amdgcn_mfma_f32_16x16x32_bf16(a, B[kb][0], acc[mt][0], 0, 0, 0);
      acc[mt][1] = __builtin_amdgcn_mfma_f32_16x16x32_bf16(a, B[kb][1], acc[mt][1], 0, 0, 0);
    }

  #pragma unroll
  for (int mt = 0; mt < 4; mt++)
    #pragma unroll
    for (int tt = 0; tt < 2; tt++)
      #pragma unroll
      for (int r = 0; r < 4; r++) {
        int v = n0 + mt * 16 + quad * 4 + r;
        if (v < NN) {
          int c = wave * 32 + tt * 16 + l16;
          out[v * D + c] = acc[mt][tt][r] + b2[c];
        }
      }
}

// ---------------------------------------------------------------------------
extern "C" void kernel_launch(void* const* d_in, const int* in_sizes, int n_in,
                              void* d_out, int out_size, void* d_ws, size_t ws_size,
                              hipStream_t stream) {
  const float* x  = (const float*)d_in[0];
  const int*   ei = (const int*)  d_in[1];   // [2, E]: src = ei, dst = ei + ED
  const float* ea = (const float*)d_in[2];
  const float* W1 = (const float*)d_in[3];
  const float* b1 = (const float*)d_in[4];
  const float* W2 = (const float*)d_in[5];
  const float* b2 = (const float*)d_in[6];
  float* out = (float*)d_out;

  char* ws = (char*)d_ws;
  size_t off = 0;
  auto alloc = [&](size_t bytes) -> void* {
    void* p = ws + off;
    off += (bytes + 255) & ~(size_t)255;
    return p;
  };
  bf16* xb       = (bf16*)alloc((size_t)NN * D * 2);
  bf16* W1p      = (bf16*)alloc(32768 * 2);
  bf16* W1bp     = (bf16*)alloc(16384 * 2);
  bf16* W2p      = (bf16*)alloc(32768 * 2);
  float* agg     = (float*)alloc((size_t)NN * D * 4);
  int* counts    = (int*)alloc(NN * 4);
  int* row_ptr   = (int*)alloc((NN + 1) * 4);
  int* fill_ptr  = (int*)alloc(NN * 4);
  int* csr_eid   = (int*)alloc((size_t)ED * 4);
  int* csr_src   = (int*)alloc((size_t)ED * 4);
  (void)ws_size; (void)in_sizes; (void)n_in; (void)out_size;  // ~13.2 MB total

  const int* src = ei;
  const int* dst = ei + ED;

  k_prep<<<705, 256, 0, stream>>>(x, W1, W2, xb, W1p, W1bp, W2p, counts);
  k_hist<<<(ED + 255) / 256, 256, 0, stream>>>(dst, counts);
  k_scan<<<1, 256, 0, stream>>>(counts, row_ptr, fill_ptr);
  k_fill<<<(ED + 255) / 256, 256, 0, stream>>>(src, dst, fill_ptr, csr_eid, csr_src);
  k_edge<<<K5_GRID, 256, 0, stream>>>(xb, ea, W1p, b1, row_ptr, csr_eid, csr_src, agg);
  k_selfterm<<<(NN + 63) / 64, 256, 0, stream>>>(xb, W1bp, row_ptr, agg);
  k_node<<<(NN + 63) / 64, 256, 0, stream>>>(agg, xb, W2p, b2, out);
}

// Round 3
// 585.921 us; speedup vs baseline: 1.0503x; 1.0503x over previous
//
#include <hip/hip_runtime.h>

// Node2Edge2Node GNN block, MI355X (gfx950) — R3: exploit full linearity.
//
//   agg[v] = (Σ_{e->v} x[src_e]) @ W1a  +  cnt_v * (x[v] @ W1b)
//          + (Σ_{e->v} ea_e)    @ W1c  +  cnt_v * b1
//   out    = [agg | x] @ W2 + b2
//
// The per-edge GEMM (62.9 GF) is gone; the hot kernel is a per-node
// segment-sum (fp32-exact) streaming ea once. Pipeline:
//   k_prep (xb cast + weight pack) -> k_hist -> k_scan -> k_fill (CSR, int2)
//   -> k_sum (wave-per-node gather-reduce) -> k_out (two fused MFMA GEMMs).

#define NN 10000
#define ED 640000
#define D  128

typedef __bf16 bf16;
typedef bf16  bf16x8 __attribute__((ext_vector_type(8)));
typedef float f32x4  __attribute__((ext_vector_type(4)));

__device__ __forceinline__ bf16 f2b(float f) {
  unsigned u = __builtin_bit_cast(unsigned, f);
  u += 0x7fffu + ((u >> 16) & 1u);               // RTNE
  unsigned short h = (unsigned short)(u >> 16);
  return __builtin_bit_cast(bf16, h);
}

__device__ __forceinline__ bf16x8 bzero8() {
  bf16 z = __builtin_bit_cast(bf16, (unsigned short)0);
  bf16x8 v = {z, z, z, z, z, z, z, z};
  return v;
}

// ---------------------------------------------------------------------------
// K1: x -> bf16; zero counts; pack W1 (384x128) and W2 (256x128) into MFMA
// B-frag layout: Bp[((kb*8 + t)*64 + L)*8 + j] = W[kb*32 + (L>>4)*8 + j][t*16 + (L&15)]
// ---------------------------------------------------------------------------
__global__ __launch_bounds__(256) void k_prep(const float* __restrict__ x,
                                              const float* __restrict__ W1,
                                              const float* __restrict__ W2,
                                              bf16* __restrict__ xb,
                                              bf16* __restrict__ W1p,
                                              bf16* __restrict__ W2p,
                                              int* __restrict__ counts) {
  int id = blockIdx.x * 256 + threadIdx.x;
  if (id < 160000) {                    // xb: 10000*128/8 chunks
    int i = id * 8;
    f32x4 a = *(const f32x4*)(x + i);
    f32x4 b = *(const f32x4*)(x + i + 4);
    bf16x8 h;
    h[0]=f2b(a[0]); h[1]=f2b(a[1]); h[2]=f2b(a[2]); h[3]=f2b(a[3]);
    h[4]=f2b(b[0]); h[5]=f2b(b[1]); h[6]=f2b(b[2]); h[7]=f2b(b[3]);
    *(bf16x8*)(xb + i) = h;
  } else if (id < 170000) {             // zero counts
    counts[id - 160000] = 0;
  } else if (id < 176144) {             // W1p: kb 0..11 (K=384, natural order)
    int o8 = id - 170000;
    int kb = o8 >> 9, rem = o8 & 511, t = rem >> 6, L = rem & 63;
    int col  = t * 16 + (L & 15);
    int row0 = kb * 32 + (L >> 4) * 8;
    bf16x8 h;
    #pragma unroll
    for (int j = 0; j < 8; j++) h[j] = f2b(W1[(row0 + j) * D + col]);
    *(bf16x8*)(W1p + o8 * 8) = h;
  } else if (id < 180240) {             // W2p: kb 0..7 (K=256)
    int o8 = id - 176144;
    int kb = o8 >> 9, rem = o8 & 511, t = rem >> 6, L = rem & 63;
    int col  = t * 16 + (L & 15);
    int row0 = kb * 32 + (L >> 4) * 8;
    bf16x8 h;
    #pragma unroll
    for (int j = 0; j < 8; j++) h[j] = f2b(W2[(row0 + j) * D + col]);
    *(bf16x8*)(W2p + o8 * 8) = h;
  }
}

// K2: histogram of dst
__global__ __launch_bounds__(256) void k_hist(const int* __restrict__ dst,
                                              int* __restrict__ counts) {
  int e = blockIdx.x * 256 + threadIdx.x;
  if (e < ED) atomicAdd(&counts[dst[e]], 1);
}

// K3: single-block exclusive scan -> row_ptr, fill_ptr
__global__ __launch_bounds__(256) void k_scan(const int* __restrict__ counts,
                                              int* __restrict__ row_ptr,
                                              int* __restrict__ fill_ptr) {
  __shared__ int part[256];
  int tid = threadIdx.x;
  const int CH = 40;                    // 256*40 = 10240 >= NN
  int base = tid * CH;
  int sum = 0;
  for (int i = 0; i < CH; i++) { int idx = base + i; if (idx < NN) sum += counts[idx]; }
  part[tid] = sum;
  __syncthreads();
  for (int off = 1; off < 256; off <<= 1) {
    int v = (tid >= off) ? part[tid - off] : 0;
    __syncthreads();
    part[tid] += v;
    __syncthreads();
  }
  int run = part[tid] - sum;            // exclusive prefix
  for (int i = 0; i < CH; i++) {
    int idx = base + i;
    if (idx < NN) { row_ptr[idx] = run; fill_ptr[idx] = run; run += counts[idx]; }
  }
  if (tid == 255) row_ptr[NN] = part[255];
}

// K4: scatter edges into CSR order, packed (eid, src) pairs
__global__ __launch_bounds__(256) void k_fill(const int* __restrict__ src,
                                              const int* __restrict__ dst,
                                              int* __restrict__ fill_ptr,
                                              int2* __restrict__ csr) {
  int e = blockIdx.x * 256 + threadIdx.x;
  if (e < ED) {
    int d = dst[e];
    int pos = atomicAdd(&fill_ptr[d], 1);
    csr[pos] = make_int2(e, src[e]);
  }
}

// ---------------------------------------------------------------------------
// K5: per-node segment sums.  sx[v] = Σ x[src_e] (fp32), sea[v] = Σ ea_e.
// One wave per node. Lane = g*16 + l: group g handles edges e0+g, e0+g+4, ...
// lane covers cols [8l, 8l+8). ea: the 327 MB HBM stream. xb: L2-resident bf16.
// No LDS, no barriers, <64 VGPR -> 8 waves/SIMD.
// ---------------------------------------------------------------------------
__global__ __launch_bounds__(256) void k_sum(const bf16*  __restrict__ xb,
                                             const float* __restrict__ ea,
                                             const int*   __restrict__ row_ptr,
                                             const int2*  __restrict__ csr,
                                             float* __restrict__ sx,
                                             float* __restrict__ sea) {
  int gwave = (blockIdx.x * 256 + threadIdx.x) >> 6;   // 0..9999
  if (gwave >= NN) return;
  int lane = threadIdx.x & 63;
  int g = lane >> 4, l = lane & 15;
  int e0 = row_ptr[gwave], e1 = row_ptr[gwave + 1];

  f32x4 ax0 = {0.f,0.f,0.f,0.f}, ax1 = {0.f,0.f,0.f,0.f};
  f32x4 ae0 = {0.f,0.f,0.f,0.f}, ae1 = {0.f,0.f,0.f,0.f};

  #pragma unroll 2
  for (int e = e0 + g; e < e1; e += 4) {
    int2 es = csr[e];
    bf16x8 hx = *(const bf16x8*)(xb + (size_t)es.y * D + l * 8);
    const float* ep = ea + (size_t)es.x * D + l * 8;
    f32x4 f0 = *(const f32x4*)ep;
    f32x4 f1 = *(const f32x4*)(ep + 4);
    ax0[0] += (float)hx[0]; ax0[1] += (float)hx[1];
    ax0[2] += (float)hx[2]; ax0[3] += (float)hx[3];
    ax1[0] += (float)hx[4]; ax1[1] += (float)hx[5];
    ax1[2] += (float)hx[6]; ax1[3] += (float)hx[7];
    ae0 += f0;
    ae1 += f1;
  }
  // reduce across the 4 groups (lane bits 4,5)
  #pragma unroll
  for (int i = 0; i < 4; i++) {
    ax0[i] += __shfl_xor(ax0[i], 16, 64); ax0[i] += __shfl_xor(ax0[i], 32, 64);
    ax1[i] += __shfl_xor(ax1[i], 16, 64); ax1[i] += __shfl_xor(ax1[i], 32, 64);
    ae0[i] += __shfl_xor(ae0[i], 16, 64); ae0[i] += __shfl_xor(ae0[i], 32, 64);
    ae1[i] += __shfl_xor(ae1[i], 16, 64); ae1[i] += __shfl_xor(ae1[i], 32, 64);
  }
  if (lane < 16) {
    float* px = sx  + (size_t)gwave * D + l * 8;
    float* pe = sea + (size_t)gwave * D + l * 8;
    *(f32x4*)px       = ax0;
    *(f32x4*)(px + 4) = ax1;
    *(f32x4*)pe       = ae0;
    *(f32x4*)(pe + 4) = ae1;
  }
}

// ---------------------------------------------------------------------------
// K6: fused per-node GEMMs.  64 nodes/block, 157 blocks.
//   stage1: agg = [sx | cnt*x | sea] @ W1 + cnt*b1          (K=384)
//   stage2: out = [bf16(agg) | xb] @ W2 + b2                (K=256)
// One LDS buffer reused: A1 stride 392 bf16, A2 stride 264 bf16.
// ---------------------------------------------------------------------------
__global__ __launch_bounds__(256) void k_out(const float* __restrict__ sx,
                                             const float* __restrict__ sea,
                                             const bf16*  __restrict__ xb,
                                             const bf16*  __restrict__ W1p,
                                             const bf16*  __restrict__ W2p,
                                             const float* __restrict__ b1,
                                             const float* __restrict__ b2,
                                             const int*   __restrict__ row_ptr,
                                             float* __restrict__ out) {
  __shared__ __align__(16) bf16 lds[64 * 392];   // 50.2 KB
  int tid  = threadIdx.x;
  int wave = tid >> 6, lane = tid & 63, quad = lane >> 4, l16 = lane & 15;
  int n0 = blockIdx.x * 64;

  // ---- stage-1 staging: A1[m][*] = [sx | cnt*x | sea] bf16, stride 392
  #pragma unroll
  for (int i = 0; i < 4; i++) {
    int m = (tid >> 4) + 16 * i;
    int v = n0 + m;
    int cl = tid & 15;
    float cntf = (v < NN) ? (float)(row_ptr[v + 1] - row_ptr[v]) : 0.f;
    #pragma unroll
    for (int j = 0; j < 3; j++) {
      int c = cl + 16 * j;              // chunk 0..47
      bf16x8 h;
      if (v < NN) {
        if (j == 0) {
          const float* p = sx + (size_t)v * D + cl * 8;
          f32x4 f0 = *(const f32x4*)p, f1 = *(const f32x4*)(p + 4);
          h[0]=f2b(f0[0]); h[1]=f2b(f0[1]); h[2]=f2b(f0[2]); h[3]=f2b(f0[3]);
          h[4]=f2b(f1[0]); h[5]=f2b(f1[1]); h[6]=f2b(f1[2]); h[7]=f2b(f1[3]);
        } else if (j == 1) {
          bf16x8 hx = *(const bf16x8*)(xb + (size_t)v * D + cl * 8);
          #pragma unroll
          for (int k = 0; k < 8; k++) h[k] = f2b((float)hx[k] * cntf);
        } else {
          const float* p = sea + (size_t)v * D + cl * 8;
          f32x4 f0 = *(const f32x4*)p, f1 = *(const f32x4*)(p + 4);
          h[0]=f2b(f0[0]); h[1]=f2b(f0[1]); h[2]=f2b(f0[2]); h[3]=f2b(f0[3]);
          h[4]=f2b(f1[0]); h[5]=f2b(f1[1]); h[6]=f2b(f1[2]); h[7]=f2b(f1[3]);
        }
      } else h = bzero8();
      *(bf16x8*)&lds[m * 392 + c * 8] = h;
    }
  }
  __syncthreads();

  // ---- stage-1 GEMM (K=384)
  f32x4 acc[4][2];
  #pragma unroll
  for (int mt = 0; mt < 4; mt++)
    #pragma unroll
    for (int tt = 0; tt < 2; tt++) acc[mt][tt] = (f32x4){0.f, 0.f, 0.f, 0.f};

  #pragma unroll
  for (int kb = 0; kb < 12; kb++) {
    bf16x8 B0 = *(const bf16x8*)(W1p + ((kb * 8 + wave * 2 + 0) * 64 + lane) * 8);
    bf16x8 B1 = *(const bf16x8*)(W1p + ((kb * 8 + wave * 2 + 1) * 64 + lane) * 8);
    #pragma unroll
    for (int mt = 0; mt < 4; mt++) {
      bf16x8 a = *(const bf16x8*)&lds[(mt * 16 + l16) * 392 + kb * 32 + quad * 8];
      acc[mt][0] = __builtin_amdgcn_mfma_f32_16x16x32_bf16(a, B0, acc[mt][0], 0, 0, 0);
      acc[mt][1] = __builtin_amdgcn_mfma_f32_16x16x32_bf16(a, B1, acc[mt][1], 0, 0, 0);
    }
  }
  __syncthreads();                      // all A1 reads done; lds reused as A2

  // ---- epilogue-1: agg = acc + cnt*b1 -> bf16 into A2 cols [0,128), stride 264
  #pragma unroll
  for (int tt = 0; tt < 2; tt++) {
    int col = wave * 32 + tt * 16 + l16;
    float bb = b1[col];
    #pragma unroll
    for (int mt = 0; mt < 4; mt++)
      #pragma unroll
      for (int r = 0; r < 4; r++) {
        int m = mt * 16 + quad * 4 + r;
        int v = n0 + m;
        float cntf = (v < NN) ? (float)(row_ptr[v + 1] - row_ptr[v]) : 0.f;
        lds[m * 264 + col] = f2b(acc[mt][tt][r] + cntf * bb);
      }
  }
  // ---- A2 cols [128,256) = xb
  #pragma unroll
  for (int i = 0; i < 4; i++) {
    int m = (tid >> 4) + 16 * i;
    int c = tid & 15;
    int v = n0 + m;
    bf16x8 h = (v < NN) ? *(const bf16x8*)(xb + (size_t)v * D + c * 8) : bzero8();
    *(bf16x8*)&lds[m * 264 + 128 + c * 8] = h;
  }
  __syncthreads();

  // ---- stage-2 GEMM (K=256)
  f32x4 acc2[4][2];
  #pragma unroll
  for (int mt = 0; mt < 4; mt++)
    #pragma unroll
    for (int tt = 0; tt < 2; tt++) acc2[mt][tt] = (f32x4){0.f, 0.f, 0.f, 0.f};

  #pragma unroll
  for (int kb = 0; kb < 8; kb++) {
    bf16x8 B0 = *(const bf16x8*)(W2p + ((kb * 8 + wave * 2 + 0) * 64 + lane) * 8);
    bf16x8 B1 = *(const bf16x8*)(W2p + ((kb * 8 + wave * 2 + 1) * 64 + lane) * 8);
    #pragma unroll
    for (int mt = 0; mt < 4; mt++) {
      bf16x8 a = *(const bf16x8*)&lds[(mt * 16 + l16) * 264 + kb * 32 + quad * 8];
      acc2[mt][0] = __builtin_amdgcn_mfma_f32_16x16x32_bf16(a, B0, acc2[mt][0], 0, 0, 0);
      acc2[mt][1] = __builtin_amdgcn_mfma_f32_16x16x32_bf16(a, B1, acc2[mt][1], 0, 0, 0);
    }
  }

  #pragma unroll
  for (int tt = 0; tt < 2; tt++) {
    int col = wave * 32 + tt * 16 + l16;
    float bb = b2[col];
    #pragma unroll
    for (int mt = 0; mt < 4; mt++)
      #pragma unroll
      for (int r = 0; r < 4; r++) {
        int v = n0 + mt * 16 + quad * 4 + r;
        if (v < NN) out[(size_t)v * D + col] = acc2[mt][tt][r] + bb;
      }
  }
}

// ---------------------------------------------------------------------------
extern "C" void kernel_launch(void* const* d_in, const int* in_sizes, int n_in,
                              void* d_out, int out_size, void* d_ws, size_t ws_size,
                              hipStream_t stream) {
  const float* x  = (const float*)d_in[0];
  const int*   ei = (const int*)  d_in[1];   // [2, E]: src = ei, dst = ei + ED
  const float* ea = (const float*)d_in[2];
  const float* W1 = (const float*)d_in[3];
  const float* b1 = (const float*)d_in[4];
  const float* W2 = (const float*)d_in[5];
  const float* b2 = (const float*)d_in[6];
  float* out = (float*)d_out;

  char* ws = (char*)d_ws;
  size_t off = 0;
  auto alloc = [&](size_t bytes) -> void* {
    void* p = ws + off;
    off += (bytes + 255) & ~(size_t)255;
    return p;
  };
  bf16*  xb      = (bf16*)alloc((size_t)NN * D * 2);
  bf16*  W1p     = (bf16*)alloc(49152 * 2);       // 384*128
  bf16*  W2p     = (bf16*)alloc(32768 * 2);       // 256*128
  float* sx      = (float*)alloc((size_t)NN * D * 4);
  float* sea     = (float*)alloc((size_t)NN * D * 4);
  int*   counts  = (int*)alloc(NN * 4);
  int*   row_ptr = (int*)alloc((NN + 1) * 4);
  int*   fill_ptr= (int*)alloc(NN * 4);
  int2*  csr     = (int2*)alloc((size_t)ED * 8);
  (void)ws_size; (void)in_sizes; (void)n_in; (void)out_size;  // ~18.5 MB

  const int* src = ei;
  const int* dst = ei + ED;

  k_prep<<<705, 256, 0, stream>>>(x, W1, W2, xb, W1p, W2p, counts);
  k_hist<<<(ED + 255) / 256, 256, 0, stream>>>(dst, counts);
  k_scan<<<1, 256, 0, stream>>>(counts, row_ptr, fill_ptr);
  k_fill<<<(ED + 255) / 256, 256, 0, stream>>>(src, dst, fill_ptr, csr);
  k_sum<<<2500, 256, 0, stream>>>(xb, ea, row_ptr, csr, sx, sea);
  k_out<<<157, 256, 0, stream>>>(sx, sea, xb, W1p, W2p, b1, b2, row_ptr, out);
}